// Round 7
// baseline (384.681 us; speedup 1.0000x reference)
//
#include <hip/hip_runtime.h>

typedef unsigned short u16;
typedef unsigned int uint32;
typedef __attribute__((ext_vector_type(8))) short short8;
typedef __attribute__((ext_vector_type(4))) float float4v;

#define N_NODES 50000
#define N_EDGES 800000
#define N_TOT   850000
#define NBH 256                          // mega_front grid = 256 blocks (1/CU, co-resident)
#define NB_BKT ((N_NODES + 255) >> 8)    // 196 coarse dst-buckets (256 nodes each)
#define NODE_BLOCKS ((N_NODES + 3) / 4)  // 12500: one wave per node

__device__ __forceinline__ float b2f(u16 u) {
  return __uint_as_float(((unsigned int)u) << 16);
}
__device__ __forceinline__ u16 f2b(float f) {
  unsigned int x = __float_as_uint(f);
  unsigned int r = (x + 0x7fffu + ((x >> 16) & 1u)) >> 16;
  return (u16)r;
}
__device__ __forceinline__ float lo_bf(uint32 g) { return __uint_as_float(g << 16); }
__device__ __forceinline__ float hi_bf(uint32 g) { return __uint_as_float(g & 0xffff0000u); }
__device__ __forceinline__ u16 conv_elem(const void* src, int i, int isf32) {
  if (isf32) return f2b(((const float*)src)[i]);
  return ((const u16*)src)[i];
}
__device__ __forceinline__ float lrelu(float a) { return (a >= 0.f) ? a : 0.2f * a; }
// edge_index element i (flat [2,E]); int64 mode reads low word (ids < 2^31)
__device__ __forceinline__ int eget(const int* __restrict__ ei, int i, int isI64) {
  return isI64 ? ei[2 * i] : ei[i];
}

// ---- device-wide barrier for the co-resident mega_front kernel ----
// 256 blocks x 256 threads = 1 block/CU: co-residency guaranteed, spin is safe.
// threadfence(release) -> arrive -> spin on coherent atomic read -> threadfence(acquire).
__device__ __forceinline__ void gbar(int* bar, int target) {
  __syncthreads();
  if (threadIdx.x == 0) {
    __threadfence();
    atomicAdd(bar, 1);
    while (atomicAdd(bar, 0) < target) __builtin_amdgcn_s_sleep(8);
    __threadfence();
  }
  __syncthreads();
}

// ---------------- mega_front: detect + W reorder + full CSR build in ONE dispatch -------
// P0: per-block inline dtype detection (deterministic, identical across blocks) +
//     W fragment reorder + att/bias convert (blocks cover 58535 items).
// P1: pack (dst<<16)|src + per-block LDS hist of dst>>8.     [barrier]
// P2: scan cnt columns (196 blocks).                          [barrier]
// P3: scan bucket totals -> bbase (block 0).                  [barrier]
// P4: scatter into bucket-contiguous staging.                 [barrier]
// P5: per-bucket degree hist + scan + row_start + self-loops + csr_dst runs +
//     edge placement into csr_src32 (196 blocks).
__global__ __launch_bounds__(256) void mega_front(
    const u16* __restrict__ x16, const int* __restrict__ ei32,
    const void* W1, const void* W2, const void* W3,
    const void* a1s, const void* a1d, const void* b1,
    const void* a2s, const void* a2d, const void* b2,
    const void* a3s, const void* a3d, const void* b3,
    int* __restrict__ flags,
    u16* __restrict__ Wf1, u16* __restrict__ Wf2, u16* __restrict__ Wf3,
    u16* __restrict__ wt,
    int* __restrict__ cnt, int* __restrict__ btotal, int* __restrict__ bbase,
    uint32* __restrict__ epack, uint32* __restrict__ staging,
    int* __restrict__ row_start, u16* __restrict__ csr_dst,
    int* __restrict__ csr_src32, int* __restrict__ bar) {
  __shared__ int shA[256];
  __shared__ int shB[256];
  __shared__ int shW[4];
  __shared__ int shF[2];
  const int tid = threadIdx.x;
  const int lane = tid & 63, wv = tid >> 6;

  // ---- P0a: inline dtype detection (every block computes the same answer) ----
  if (tid == 0) { shF[0] = 0; shF[1] = 0; }
  __syncthreads();
  {
    int emax = 0;
    for (int i = tid; i < 4096; i += 256) {
      int e = (x16[i] >> 7) & 0xFF;  // bf16 exponent field
      emax = emax > e ? emax : e;
    }
    if (emax >= 140) atomicOr(&shF[0], 1);            // |v| >= 2^13: not real bf16 N(0,1)
    if (ei32[2 * tid + 1] != 0) atomicOr(&shF[1], 1); // nonzero odd word => int32 data
  }
  __syncthreads();
  const int f32 = shF[0];
  const int i64 = shF[1] ? 0 : 1;
  if (blockIdx.x == 0 && tid == 0) { flags[0] = f32; flags[1] = i64; }

  // ---- P0b: W fragment reorder + att/bias convert ----
  {
    int idx = blockIdx.x * 256 + tid;
    if (idx < 57344) {
      const void* W; u16* Wf; int NCOLS, li;
      if (idx < 16384)      { W = W1; Wf = Wf1; NCOLS = 128; li = idx; }
      else if (idx < 32768) { W = W2; Wf = Wf2; NCOLS = 128; li = idx - 16384; }
      else                  { W = W3; Wf = Wf3; NCOLS = 188; li = idx - 32768; }
      int j = li & 7;
      int l = (li >> 3) & 63;
      int c = (li >> 9) & 3;
      int t = li >> 11;
      int k = c * 32 + (l >> 4) * 8 + j;
      int n = t * 16 + (l & 15);
      Wf[li] = (n < NCOLS) ? conv_elem(W, k * NCOLS + n, f32) : (u16)0;
    } else if (idx < 58535) {
      int li = idx - 57344;
      const void* src; int off;
      if (li < 128)       { src = a1s; off = 16384; }
      else if (li < 256)  { src = a1d; off = 16512; li -= 128; }
      else if (li < 384)  { src = b1;  off = 16640; li -= 256; }
      else if (li < 512)  { src = a2s; off = 33152; li -= 384; }
      else if (li < 640)  { src = a2d; off = 33280; li -= 512; }
      else if (li < 768)  { src = b2;  off = 33408; li -= 640; }
      else if (li < 956)  { src = a3s; off = 57600; li -= 768; }
      else if (li < 1144) { src = a3d; off = 57788; li -= 956; }
      else                { src = b3;  off = 57976; li -= 1144; }
      wt[off + li] = conv_elem(src, li, f32);
    }
  }

  // ---- P1: pack + per-block histogram ----
  for (int t = tid; t < NB_BKT; t += 256) shA[t] = 0;
  __syncthreads();
  const int chunk = (N_EDGES + NBH - 1) / NBH;
  const int elo = blockIdx.x * chunk;
  const int ehi = min(elo + chunk, N_EDGES);
  for (int e = elo + tid; e < ehi; e += 256) {
    int s = eget(ei32, e, i64);
    int d = eget(ei32, N_EDGES + e, i64);
    epack[e] = ((uint32)d << 16) | (uint32)s;
    atomicAdd(&shA[d >> 8], 1);
  }
  __syncthreads();
  for (int t = tid; t < NB_BKT; t += 256) cnt[t * NBH + blockIdx.x] = shA[t];

  gbar(bar, NBH);  // cnt complete

  // ---- P2: exclusive scan of cnt rows + bucket totals ----
  if (blockIdx.x < NB_BKT) {
    const int bkt = blockIdx.x;
    int v = cnt[bkt * NBH + tid];
    int incl = v;
#pragma unroll
    for (int off = 1; off < 64; off <<= 1) {
      int t = __shfl_up(incl, off, 64);
      if (lane >= off) incl += t;
    }
    if (lane == 63) shW[wv] = incl;
    __syncthreads();
    if (tid == 0) {
      int s = 0;
#pragma unroll
      for (int w = 0; w < 4; w++) { int t = shW[w]; shW[w] = s; s += t; }
      btotal[bkt] = s;
    }
    __syncthreads();
    cnt[bkt * NBH + tid] = shW[wv] + incl - v;
  }

  gbar(bar, 2 * NBH);  // scans + totals complete

  // ---- P3: scan bucket totals -> bbase ----
  if (blockIdx.x == 0) {
    int v = (tid < NB_BKT) ? btotal[tid] : 0;
    int incl = v;
#pragma unroll
    for (int off = 1; off < 64; off <<= 1) {
      int t = __shfl_up(incl, off, 64);
      if (lane >= off) incl += t;
    }
    if (lane == 63) shW[wv] = incl;
    __syncthreads();
    if (tid == 0) {
      int s = 0;
#pragma unroll
      for (int w = 0; w < 4; w++) { int t = shW[w]; shW[w] = s; s += t; }
      bbase[NB_BKT] = s;
    }
    __syncthreads();
    if (tid < NB_BKT) bbase[tid] = shW[wv] + incl - v;
  }

  gbar(bar, 3 * NBH);  // bbase complete

  // ---- P4: scatter into bucket-contiguous staging ----
  for (int t = tid; t < NB_BKT; t += 256)
    shA[t] = bbase[t] + cnt[t * NBH + blockIdx.x];
  __syncthreads();
  for (int e = elo + tid; e < ehi; e += 256) {
    uint32 pk = epack[e];
    int p = atomicAdd(&shA[pk >> 24], 1);  // bkt = d>>8 = pk>>24
    staging[p] = pk;
  }

  gbar(bar, 4 * NBH);  // staging complete

  // ---- P5: per-bucket degree hist + scan + row_start + self-loops + placement ----
  if (blockIdx.x < NB_BKT) {
    const int b = blockIdx.x;
    shA[tid] = 0;
    __syncthreads();
    const int lo = bbase[b], hi = bbase[b + 1];
    for (int i = lo + tid; i < hi; i += 256)
      atomicAdd(&shA[(staging[i] >> 16) & 255], 1);
    __syncthreads();
    int v = shA[tid];
    int incl = v;
#pragma unroll
    for (int off = 1; off < 64; off <<= 1) {
      int t = __shfl_up(incl, off, 64);
      if (lane >= off) incl += t;
    }
    if (lane == 63) shW[wv] = incl;
    __syncthreads();
    if (tid == 0) {
      int s = 0;
#pragma unroll
      for (int w = 0; w < 4; w++) { int t = shW[w]; shW[w] = s; s += t; }
    }
    __syncthreads();
    int excl = shW[wv] + incl - v;
    const int n = (b << 8) + tid;
    if (n < N_NODES) {
      int rs = lo + (b << 8) + excl + tid;  // edges-before + selfloops-before
      row_start[n] = rs;
      csr_src32[rs] = n;  // self-loop at slot rs
      u16 g16 = (u16)n;
      for (int k = 0; k <= v; k++) csr_dst[rs + k] = g16;
      shB[tid] = rs + 1;
    }
    if (b == NB_BKT - 1 && tid == 0) row_start[N_NODES] = N_TOT;
    __syncthreads();
    for (int i = lo + tid; i < hi; i += 256) {
      uint32 pk = staging[i];
      int p = atomicAdd(&shB[(pk >> 16) & 255], 1);
      csr_src32[p] = (int)(pk & 0xffffu);
    }
  }
}

// ---------------- MFMA GEMM: H[M,NCOLS] = X[M,128] @ W[128,NCOLS] ----------------
// One wave per 16-row tile. B from fragment-ordered Wf (L2-resident). No LDS.
// RAWX: A is the raw input x (fp32 or bf16 per flags[0]); conversion fused into
//       the fragment load.
// FUSE_A (layers 1/2): head h owns tiles 2h,2h+1 -> logits in epilogue.
// CMAJOR+FUSE3 (layer 3): class-major store, head-masked logit accumulation,
//       and bf16 1.0 written into pad cols 188..191 (the aggregate3 den column).
template <int NT, int NCOLS, int STRIDE, bool FUSE_A, bool CMAJOR, bool FUSE3, bool RAWX>
__global__ __launch_bounds__(256) void gemm_mfma(const void* __restrict__ X,
                                                 const u16* __restrict__ Wf,
                                                 const u16* __restrict__ attS,
                                                 const u16* __restrict__ attD,
                                                 const int* __restrict__ flags,
                                                 u16* __restrict__ H,
                                                 float* __restrict__ a_s,
                                                 float* __restrict__ a_d, int M) {
  // readfirstlane: prove wave-uniformity of the wave id to the compiler (SGPR loops/addrs)
  const int wid = __builtin_amdgcn_readfirstlane(threadIdx.x >> 6);
  const int lane = threadIdx.x & 63;
  const int row0 = (blockIdx.x * 4 + wid) * 16;
  if (row0 >= M) return;
  const int qr = lane >> 4;   // quad: k-subchunk for A/B, row group for C/D
  const int ln = lane & 15;   // A row within tile / C col within tile

  float4v acc[NT];
#pragma unroll
  for (int t = 0; t < NT; t++) acc[t] = (float4v){0.f, 0.f, 0.f, 0.f};

  const short8* Wf8 = (const short8*)Wf;  // [(t*4 + c)*64 + lane]
  const size_t aoff = (size_t)(row0 + ln) * 128 + qr * 8;
  int f32m = 0;
  if constexpr (RAWX) f32m = flags[0];

#pragma unroll
  for (int c = 0; c < 4; c++) {
    short8 afrag;
    if constexpr (RAWX) {
      if (f32m) {
        const float* ap = (const float*)X + aoff + c * 32;
        float4 lo = ((const float4*)ap)[0];
        float4 hi = ((const float4*)ap)[1];
        afrag[0] = (short)f2b(lo.x); afrag[1] = (short)f2b(lo.y);
        afrag[2] = (short)f2b(lo.z); afrag[3] = (short)f2b(lo.w);
        afrag[4] = (short)f2b(hi.x); afrag[5] = (short)f2b(hi.y);
        afrag[6] = (short)f2b(hi.z); afrag[7] = (short)f2b(hi.w);
      } else {
        afrag = *(const short8*)((const u16*)X + aoff + c * 32);
      }
    } else {
      afrag = *(const short8*)((const u16*)X + aoff + c * 32);
    }
#pragma unroll
    for (int t = 0; t < NT; t++) {
      short8 bfrag = Wf8[(t * 4 + c) * 64 + lane];
      acc[t] = __builtin_amdgcn_mfma_f32_16x16x32_bf16(afrag, bfrag, acc[t], 0, 0, 0);
    }
  }

  // store H (D layout: row = qr*4 + i, col = t*16 + ln)
#pragma unroll
  for (int t = 0; t < NT; t++) {
    int col = t * 16 + ln;
    if (col < NCOLS) {
      int off;
      if constexpr (CMAJOR) {
        int h = (col >= 141) ? 3 : (col >= 94) ? 2 : (col >= 47) ? 1 : 0;
        int c = col - h * 47;
        off = c * 4 + h;
      } else {
        off = col;
      }
#pragma unroll
      for (int i = 0; i < 4; i++) {
        H[(size_t)(row0 + qr * 4 + i) * STRIDE + off] = f2b(acc[t][i]);
      }
    } else {
      if constexpr (CMAJOR) {
        // pad cols 188..191: bf16 1.0 -> aggregate3's den pseudo-class (uint2 col 47)
#pragma unroll
        for (int i = 0; i < 4; i++) {
          H[(size_t)(row0 + qr * 4 + i) * STRIDE + col] = (u16)0x3F80;
        }
      }
    }
  }

  if constexpr (FUSE_A) {
    float aSf[NT], aDf[NT];
#pragma unroll
    for (int t = 0; t < NT; t++) {
      aSf[t] = b2f(attS[t * 16 + ln]);
      aDf[t] = b2f(attD[t * 16 + ln]);
    }
#pragma unroll
    for (int h = 0; h < 4; h++) {
#pragma unroll
      for (int i = 0; i < 4; i++) {
        float s = acc[2 * h][i] * aSf[2 * h] + acc[2 * h + 1][i] * aSf[2 * h + 1];
        float d = acc[2 * h][i] * aDf[2 * h] + acc[2 * h + 1][i] * aDf[2 * h + 1];
#pragma unroll
        for (int m = 1; m < 16; m <<= 1) {
          s += __shfl_xor(s, m, 64);
          d += __shfl_xor(d, m, 64);
        }
        if (ln == 0) {
          int r = row0 + qr * 4 + i;
          a_s[r * 4 + h] = s;
          a_d[r * 4 + h] = d;
        }
      }
    }
  }

  if constexpr (FUSE3) {
    // a_s[n][h] = sum_c H[n][h*47+c] * attS[h*47+c]; col = h*47+c indexes attS directly.
    float sh[4][4], dh[4][4];  // [head][i]
#pragma unroll
    for (int h = 0; h < 4; h++)
#pragma unroll
      for (int i = 0; i < 4; i++) { sh[h][i] = 0.f; dh[h][i] = 0.f; }
#pragma unroll
    for (int t = 0; t < NT; t++) {
      int col = t * 16 + ln;
      bool v = (col < NCOLS);
      float aS = v ? b2f(attS[col]) : 0.f;
      float aD = v ? b2f(attD[col]) : 0.f;
      int hh = (col >= 141) ? 3 : (col >= 94) ? 2 : (col >= 47) ? 1 : 0;
      float aS0 = (hh == 0) ? aS : 0.f, aS1 = (hh == 1) ? aS : 0.f;
      float aS2 = (hh == 2) ? aS : 0.f, aS3 = (hh == 3) ? aS : 0.f;
      float aD0 = (hh == 0) ? aD : 0.f, aD1 = (hh == 1) ? aD : 0.f;
      float aD2 = (hh == 2) ? aD : 0.f, aD3 = (hh == 3) ? aD : 0.f;
#pragma unroll
      for (int i = 0; i < 4; i++) {
        float a = acc[t][i];
        sh[0][i] += a * aS0; sh[1][i] += a * aS1;
        sh[2][i] += a * aS2; sh[3][i] += a * aS3;
        dh[0][i] += a * aD0; dh[1][i] += a * aD1;
        dh[2][i] += a * aD2; dh[3][i] += a * aD3;
      }
    }
#pragma unroll
    for (int h = 0; h < 4; h++) {
#pragma unroll
      for (int i = 0; i < 4; i++) {
        float s = sh[h][i], d = dh[h][i];
#pragma unroll
        for (int m = 1; m < 16; m <<= 1) {
          s += __shfl_xor(s, m, 64);
          d += __shfl_xor(d, m, 64);
        }
        if (ln == 0) {
          int r = row0 + qr * 4 + i;
          a_s[r * 4 + h] = s;
          a_d[r * 4 + h] = d;
        }
      }
    }
  }
}

// ---------------- per-edge softmax weights for layer 3 (unnormalized, packed bf16x4) ----
// w[e][h] = exp(leaky(a_s[src][h] + a_d[dst][h])) as bf16. Self-normalizing: den sums
// the same bf16 values (via the ones pseudo-class), so ratios carry ~2^-9 rel error.
__global__ __launch_bounds__(256) void edge_weights(const int* __restrict__ csr_src,
                                                    const u16* __restrict__ csr_dst,
                                                    const float* __restrict__ a_s,
                                                    const float* __restrict__ a_d,
                                                    uint2* __restrict__ w, int nE) {
  int e = blockIdx.x * blockDim.x + threadIdx.x;
  if (e >= nE) return;
  int s = csr_src[e], d = csr_dst[e];
  float4 as = ((const float4*)a_s)[s];
  float4 ad = ((const float4*)a_d)[d];
  float w0 = __expf(lrelu(as.x + ad.x));
  float w1 = __expf(lrelu(as.y + ad.y));
  float w2 = __expf(lrelu(as.z + ad.z));
  float w3 = __expf(lrelu(as.w + ad.w));
  uint2 o;
  o.x = ((uint32)f2b(w1) << 16) | (uint32)f2b(w0);
  o.y = ((uint32)f2b(w3) << 16) | (uint32)f2b(w2);
  w[e] = o;
}

// ---------------- aggregation (one node per wave; wave-uniform scalar metadata) ----------

// layers 1/2: lane L owns cols 2L,2L+1 (head L>>4). One uint gather/edge/lane.
// Edge weights computed INLINE (fp32, per-lane independent -> no shuffles).
// 8-deep unroll: more outstanding gathers per wave.
__global__ __launch_bounds__(256) void aggregate12(const u16* __restrict__ h,
                                                   const float* __restrict__ a_s,
                                                   const float* __restrict__ a_d,
                                                   const int* __restrict__ row_start,
                                                   const int* __restrict__ csr_src,
                                                   const u16* __restrict__ bias,
                                                   u16* __restrict__ out, int nN) {
  const int lane = threadIdx.x & 63;
  const int wid = __builtin_amdgcn_readfirstlane(threadIdx.x >> 6);  // SGPR wave id
  const int n = blockIdx.x * 4 + wid;
  if (n >= nN) return;
  const int hL = lane >> 4;  // head of cols 2L, 2L+1
  const uint32* h32 = (const uint32*)h;
  const float bias0 = b2f(bias[2 * lane]);
  const float bias1 = b2f(bias[2 * lane + 1]);
  const float adv = a_d[n * 4 + hL];  // wave-row uniform, per head group
  int beg = row_start[n], end = row_start[n + 1];

  float acc0 = 0.f, acc1 = 0.f, den = 0.f;
  int e = beg;
  for (; e + 7 < end; e += 8) {
    int s[8];
    float av[8];
    uint32 g[8];
#pragma unroll
    for (int j = 0; j < 8; j++) s[j] = csr_src[e + j];
#pragma unroll
    for (int j = 0; j < 8; j++) av[j] = a_s[s[j] * 4 + hL];
#pragma unroll
    for (int j = 0; j < 8; j++) g[j] = h32[s[j] * 64 + lane];
#pragma unroll
    for (int j = 0; j < 8; j++) {
      float w = __expf(lrelu(av[j] + adv));
      den += w;
      acc0 += w * lo_bf(g[j]);
      acc1 += w * hi_bf(g[j]);
    }
  }
  for (; e + 3 < end; e += 4) {
    int s[4];
    float av[4];
    uint32 g[4];
#pragma unroll
    for (int j = 0; j < 4; j++) s[j] = csr_src[e + j];
#pragma unroll
    for (int j = 0; j < 4; j++) av[j] = a_s[s[j] * 4 + hL];
#pragma unroll
    for (int j = 0; j < 4; j++) g[j] = h32[s[j] * 64 + lane];
#pragma unroll
    for (int j = 0; j < 4; j++) {
      float w = __expf(lrelu(av[j] + adv));
      den += w;
      acc0 += w * lo_bf(g[j]);
      acc1 += w * hi_bf(g[j]);
    }
  }
  for (; e < end; ++e) {
    int s = csr_src[e];
    float w = __expf(lrelu(a_s[s * 4 + hL] + adv));
    uint32 g = h32[s * 64 + lane];
    den += w;
    acc0 += w * lo_bf(g);
    acc1 += w * hi_bf(g);
  }
  float inv = 1.0f / den;
  float o0 = fmaxf(acc0 * inv + bias0, 0.f);  // relu between layers
  float o1 = fmaxf(acc1 * inv + bias1, 0.f);
  uint32 packed = ((uint32)f2b(o1) << 16) | (uint32)f2b(o0);
  ((uint32*)out)[n * 64 + lane] = packed;
}

// layer 3: class-major h3 (uint2 gather = 4 head vals for class `lane`).
// Weights from the precomputed wbuf (wave-uniform broadcast load, no shuffles
// in the loop); den comes free from the ones pseudo-class accumulated in
// lane 47. mean over heads + bias + log_softmax.
__global__ __launch_bounds__(256) void aggregate3(const u16* __restrict__ h3,
                                                  const uint2* __restrict__ wbuf,
                                                  const int* __restrict__ row_start,
                                                  const int* __restrict__ csr_src,
                                                  const u16* __restrict__ b3,
                                                  const int* __restrict__ flags,
                                                  void* __restrict__ out, int nN) {
  const int lane = threadIdx.x & 63;
  const int wid = __builtin_amdgcn_readfirstlane(threadIdx.x >> 6);  // SGPR wave id
  const int n = blockIdx.x * 4 + wid;
  if (n >= nN) return;
  const bool act = lane < 47;
  const int lidx = (lane <= 47) ? lane : 0;  // lane 47 reads the ones-column -> den
  const float b3v = act ? b2f(b3[lane]) : 0.f;
  const int isf32 = flags[0];
  const uint2* h3v = (const uint2*)h3;  // row = 48 uint2
  int beg = row_start[n], end = row_start[n + 1];

  float acc0 = 0.f, acc1 = 0.f, acc2 = 0.f, acc3 = 0.f;
  int e = beg;
  for (; e + 7 < end; e += 8) {
    int s[8];
    uint2 wp[8];
    uint2 g[8];
#pragma unroll
    for (int j = 0; j < 8; j++) s[j] = csr_src[e + j];
#pragma unroll
    for (int j = 0; j < 8; j++) wp[j] = wbuf[e + j];
#pragma unroll
    for (int j = 0; j < 8; j++) g[j] = h3v[(size_t)s[j] * 48 + lidx];
#pragma unroll
    for (int j = 0; j < 8; j++) {
      float w0 = lo_bf(wp[j].x), w1 = hi_bf(wp[j].x);
      float w2 = lo_bf(wp[j].y), w3 = hi_bf(wp[j].y);
      acc0 += w0 * lo_bf(g[j].x);
      acc1 += w1 * hi_bf(g[j].x);
      acc2 += w2 * lo_bf(g[j].y);
      acc3 += w3 * hi_bf(g[j].y);
    }
  }
  for (; e + 3 < end; e += 4) {
    int s[4];
    uint2 wp[4];
    uint2 g[4];
#pragma unroll
    for (int j = 0; j < 4; j++) s[j] = csr_src[e + j];
#pragma unroll
    for (int j = 0; j < 4; j++) wp[j] = wbuf[e + j];
#pragma unroll
    for (int j = 0; j < 4; j++) g[j] = h3v[(size_t)s[j] * 48 + lidx];
#pragma unroll
    for (int j = 0; j < 4; j++) {
      float w0 = lo_bf(wp[j].x), w1 = hi_bf(wp[j].x);
      float w2 = lo_bf(wp[j].y), w3 = hi_bf(wp[j].y);
      acc0 += w0 * lo_bf(g[j].x);
      acc1 += w1 * hi_bf(g[j].x);
      acc2 += w2 * lo_bf(g[j].y);
      acc3 += w3 * hi_bf(g[j].y);
    }
  }
  for (; e < end; ++e) {
    int s = csr_src[e];
    uint2 wp = wbuf[e];
    uint2 g = h3v[(size_t)s * 48 + lidx];
    float w0 = lo_bf(wp.x), w1 = hi_bf(wp.x);
    float w2 = lo_bf(wp.y), w3 = hi_bf(wp.y);
    acc0 += w0 * lo_bf(g.x);
    acc1 += w1 * hi_bf(g.x);
    acc2 += w2 * lo_bf(g.y);
    acc3 += w3 * hi_bf(g.y);
  }
  // dens live in lane 47's accumulators (w * 1.0 sums, same add order as explicit den)
  float den0 = __shfl(acc0, 47, 64);
  float den1 = __shfl(acc1, 47, 64);
  float den2 = __shfl(acc2, 47, 64);
  float den3 = __shfl(acc3, 47, 64);
  float val = act ? 0.25f * (acc0 / den0 + acc1 / den1 + acc2 / den2 + acc3 / den3) + b3v
                  : -1e30f;
  float mx = val;
#pragma unroll
  for (int m = 1; m < 64; m <<= 1) mx = fmaxf(mx, __shfl_xor(mx, m, 64));
  float ex = act ? __expf(val - mx) : 0.f;
  float sm = ex;
#pragma unroll
  for (int m = 1; m < 64; m <<= 1) sm += __shfl_xor(sm, m, 64);
  float lse = mx + __logf(sm);
  if (act) {
    float r = val - lse;
    if (isf32) ((float*)out)[n * 47 + lane] = r;
    else       ((u16*)out)[n * 47 + lane] = f2b(r);
  }
}

// ---------------- launch ----------------

extern "C" void kernel_launch(void* const* d_in, const int* in_sizes, int n_in,
                              void* d_out, int out_size, void* d_ws, size_t ws_size,
                              hipStream_t stream) {
  const void* x   = d_in[0];
  const void* ei  = d_in[1];
  const void* W1  = d_in[2];
  const void* a1s = d_in[3];
  const void* a1d = d_in[4];
  const void* b1  = d_in[5];
  const void* W2  = d_in[6];
  const void* a2s = d_in[7];
  const void* a2d = d_in[8];
  const void* b2  = d_in[9];
  const void* W3  = d_in[10];
  const void* a3s = d_in[11];
  const void* a3d = d_in[12];
  const void* b3  = d_in[13];
  const int* ei32 = (const int*)ei;

  auto au = [](size_t v) { return (v + 255) & ~(size_t)255; };
  char* p = (char*)d_ws;
  int* flags     = (int*)p; p += 256;
  int* bar       = (int*)p; p += 256;
  u16* wt        = (u16*)p; p += au((size_t)58023 * 2);
  u16* Wf1       = (u16*)p; p += au((size_t)16384 * 2);
  u16* Wf2       = (u16*)p; p += au((size_t)16384 * 2);
  u16* Wf3       = (u16*)p; p += au((size_t)24576 * 2);
  int* row_start = (int*)p; p += au((size_t)(N_NODES + 1) * 4);
  int* cnt       = (int*)p; p += au((size_t)NB_BKT * NBH * 4);
  int* btotal    = (int*)p; p += au((size_t)NB_BKT * 4);
  int* bbase     = (int*)p; p += au((size_t)(NB_BKT + 1) * 4);
  int* csr_src32 = (int*)p; p += au((size_t)N_TOT * 4);
  u16* csr_dst   = (u16*)p; p += au((size_t)N_TOT * 2);
  uint2* wbuf    = (uint2*)p; p += au((size_t)N_TOT * 8);
  float* a_s     = (float*)p; p += au((size_t)N_NODES * 4 * 4);
  float* a_d     = (float*)p; p += au((size_t)N_NODES * 4 * 4);
  u16* hB        = (u16*)p; p += au((size_t)N_NODES * 128 * 2);
  u16* hA        = (u16*)p; p += au((size_t)N_NODES * 128 * 2);
  u16* h3        = (u16*)p; p += au((size_t)N_NODES * 192 * 2);
  // epack/staging alias h3: both consumed before layer 3 writes h3.
  uint32* epack   = (uint32*)h3;               // 3.2 MB
  uint32* staging = (uint32*)(h3 + 1600000);   // next 3.2 MB

  const u16* a1sc = wt + 16384;
  const u16* a1dc = wt + 16512;
  const u16* b1c  = wt + 16640;
  const u16* a2sc = wt + 33152;
  const u16* a2dc = wt + 33280;
  const u16* b2c  = wt + 33408;
  const u16* a3sc = wt + 57600;
  const u16* a3dc = wt + 57788;
  const u16* b3c  = wt + 57976;

  const int gemmBlocks = (N_NODES / 16 + 3) / 4;   // wave per 16-row tile: 782
  const int edgeBlocks = (N_TOT + 255) / 256;

  // barrier counter must start at 0 each iteration
  hipMemsetAsync(bar, 0, 4, stream);

  // front end: dtype detect + W reorder + full CSR build (one dispatch, 4 grid barriers)
  mega_front<<<NBH, 256, 0, stream>>>((const u16*)x, ei32, W1, W2, W3,
                                      a1s, a1d, b1, a2s, a2d, b2, a3s, a3d, b3,
                                      flags, Wf1, Wf2, Wf3, wt,
                                      cnt, btotal, bbase, epack, staging,
                                      row_start, csr_dst, csr_src32, bar);

  // layer 1 (x conversion fused into A-load; logits fused into GEMM epilogue;
  //          weights fused into aggregate)
  gemm_mfma<8, 128, 128, true, false, false, true><<<gemmBlocks, 256, 0, stream>>>(
      x, Wf1, a1sc, a1dc, flags, hA, a_s, a_d, N_NODES);
  aggregate12<<<NODE_BLOCKS, 256, 0, stream>>>(hA, a_s, a_d, row_start, csr_src32,
                                               b1c, hB, N_NODES);

  // layer 2
  gemm_mfma<8, 128, 128, true, false, false, false><<<gemmBlocks, 256, 0, stream>>>(
      hB, Wf2, a2sc, a2dc, flags, hA, a_s, a_d, N_NODES);
  aggregate12<<<NODE_BLOCKS, 256, 0, stream>>>(hA, a_s, a_d, row_start, csr_src32,
                                               b2c, hB, N_NODES);

  // layer 3 (h3 class-major + ones pad col; logits fused via head-masked reduce;
  //          weights precomputed per edge; den from the ones pseudo-class)
  gemm_mfma<12, 188, 192, false, true, true, false><<<gemmBlocks, 256, 0, stream>>>(
      hB, Wf3, a3sc, a3dc, flags, h3, a_s, a_d, N_NODES);
  edge_weights<<<edgeBlocks, 256, 0, stream>>>(csr_src32, csr_dst, a_s, a_d, wbuf, N_TOT);
  aggregate3<<<NODE_BLOCKS, 256, 0, stream>>>(h3, wbuf, row_start, csr_src32,
                                              b3c, flags, d_out, N_NODES);
}

// Round 8
// 303.831 us; speedup vs baseline: 1.2661x; 1.2661x over previous
//
#include <hip/hip_runtime.h>

typedef unsigned short u16;
typedef unsigned int uint32;
typedef __attribute__((ext_vector_type(8))) short short8;
typedef __attribute__((ext_vector_type(4))) float float4v;

#define N_NODES 50000
#define N_EDGES 800000
#define N_TOT   850000
#define NBH 256                          // blocks for hist/scatter passes
#define NB_BKT ((N_NODES + 255) >> 8)    // 196 coarse dst-buckets (256 nodes each)
#define NODE_BLOCKS ((N_NODES + 3) / 4)  // 12500: one wave per node

__device__ __forceinline__ float b2f(u16 u) {
  return __uint_as_float(((unsigned int)u) << 16);
}
__device__ __forceinline__ u16 f2b(float f) {
  unsigned int x = __float_as_uint(f);
  unsigned int r = (x + 0x7fffu + ((x >> 16) & 1u)) >> 16;
  return (u16)r;
}
__device__ __forceinline__ float lo_bf(uint32 g) { return __uint_as_float(g << 16); }
__device__ __forceinline__ float hi_bf(uint32 g) { return __uint_as_float(g & 0xffff0000u); }
__device__ __forceinline__ u16 conv_elem(const void* src, int i, int isf32) {
  if (isf32) return f2b(((const float*)src)[i]);
  return ((const u16*)src)[i];
}
__device__ __forceinline__ float lrelu(float a) { return (a >= 0.f) ? a : 0.2f * a; }
// edge_index element i (flat [2,E]); int64 mode reads low word (ids < 2^31)
__device__ __forceinline__ int eget(const int* __restrict__ ei, int i, int isI64) {
  return isI64 ? ei[2 * i] : ei[i];
}

// ---------------- W fragment reorder + att/bias convert (+ inline f32 detect) ----------
// Wf[t][c][lane][j] = W[c*32 + (lane>>4)*8 + j][t*16 + (lane&15)], zero-padded.
// Tail threads (idx >= 57344) convert the 1063 att/bias elements into wt.
// f32 detection computed per-block (deterministic, identical result in every block);
// block 0 publishes flags[0] for gemm1/aggregate3.
__global__ void reorder_all(const u16* __restrict__ x16,
                            const void* W1, const void* W2, const void* W3,
                            const void* a1s, const void* a1d, const void* b1,
                            const void* a2s, const void* a2d, const void* b2,
                            const void* a3s, const void* a3d, const void* b3,
                            int* __restrict__ flags,
                            u16* __restrict__ Wf1, u16* __restrict__ Wf2,
                            u16* __restrict__ Wf3, u16* __restrict__ wt) {
  __shared__ int shF;
  const int tid = threadIdx.x;
  if (tid == 0) shF = 0;
  __syncthreads();
  {
    int emax = 0;
    for (int i = tid; i < 4096; i += 256) {
      int e = (x16[i] >> 7) & 0xFF;  // bf16 exponent field
      emax = emax > e ? emax : e;
    }
    if (emax >= 140) atomicOr(&shF, 1);  // |v| >= 2^13: impossible for real bf16 N(0,1)
  }
  __syncthreads();
  const int f32 = shF;
  if (blockIdx.x == 0 && tid == 0) flags[0] = f32;

  int idx = blockIdx.x * 256 + tid;
  if (idx < 57344) {
    const void* W; u16* Wf; int NCOLS, li;
    if (idx < 16384)      { W = W1; Wf = Wf1; NCOLS = 128; li = idx; }
    else if (idx < 32768) { W = W2; Wf = Wf2; NCOLS = 128; li = idx - 16384; }
    else                  { W = W3; Wf = Wf3; NCOLS = 188; li = idx - 32768; }
    int j = li & 7;
    int l = (li >> 3) & 63;
    int c = (li >> 9) & 3;
    int t = li >> 11;
    int k = c * 32 + (l >> 4) * 8 + j;
    int n = t * 16 + (l & 15);
    Wf[li] = (n < NCOLS) ? conv_elem(W, k * NCOLS + n, f32) : (u16)0;
  } else if (idx < 58535) {
    int li = idx - 57344;
    const void* src; int off;
    if (li < 128)       { src = a1s; off = 16384; }
    else if (li < 256)  { src = a1d; off = 16512; li -= 128; }
    else if (li < 384)  { src = b1;  off = 16640; li -= 256; }
    else if (li < 512)  { src = a2s; off = 33152; li -= 384; }
    else if (li < 640)  { src = a2d; off = 33280; li -= 512; }
    else if (li < 768)  { src = b2;  off = 33408; li -= 640; }
    else if (li < 956)  { src = a3s; off = 57600; li -= 768; }
    else if (li < 1144) { src = a3d; off = 57788; li -= 956; }
    else                { src = b3;  off = 57976; li -= 1144; }
    wt[off + li] = conv_elem(src, li, f32);
  }
}

// ---------------- CSR build (NO global atomics, NO grid barriers) ----------------
// Coarse counting-sort by dst-bucket (256 nodes/bucket), all atomics in LDS:
//   pack_hist -> scan_cols -> scatter_coarse -> build_csr.
// Bucket bases are recomputed redundantly in LDS from btotal (196-elem scan,
// ~1us) inside scatter_coarse and build_csr — no scan_base dispatch.

// pass 1: pack (dst<<16)|src + per-block LDS hist of dst>>8 (+ inline i64 detect).
__global__ __launch_bounds__(256) void pack_hist(const int* __restrict__ ei,
                                                 uint32* __restrict__ epack,
                                                 int* __restrict__ cnt) {
  __shared__ int hist[NB_BKT];
  __shared__ int shI;
  const int tid = threadIdx.x;
  if (tid == 0) shI = 0;
  for (int t = tid; t < NB_BKT; t += 256) hist[t] = 0;
  __syncthreads();
  if (ei[2 * tid + 1] != 0) atomicOr(&shI, 1);  // nonzero odd word => int32 data
  __syncthreads();
  const int i64 = shI ? 0 : 1;
  const int chunk = (N_EDGES + NBH - 1) / NBH;
  const int lo = blockIdx.x * chunk;
  const int hi = min(lo + chunk, N_EDGES);
  for (int e = lo + tid; e < hi; e += 256) {
    int s = eget(ei, e, i64);
    int d = eget(ei, N_EDGES + e, i64);
    epack[e] = ((uint32)d << 16) | (uint32)s;
    atomicAdd(&hist[d >> 8], 1);
  }
  __syncthreads();
  for (int t = tid; t < NB_BKT; t += 256) cnt[t * NBH + blockIdx.x] = hist[t];
}

// exclusive scan of cnt[bkt][0..NBH) along the block axis (in place) + bucket totals.
__global__ __launch_bounds__(256) void scan_cols(int* __restrict__ cnt,
                                                 int* __restrict__ total) {
  __shared__ int ws[4];
  const int bkt = blockIdx.x;
  const int tid = threadIdx.x, lane = tid & 63, wv = tid >> 6;
  int v = cnt[bkt * NBH + tid];
  int incl = v;
#pragma unroll
  for (int off = 1; off < 64; off <<= 1) {
    int t = __shfl_up(incl, off, 64);
    if (lane >= off) incl += t;
  }
  if (lane == 63) ws[wv] = incl;
  __syncthreads();
  if (tid == 0) {
    int s = 0;
#pragma unroll
    for (int w = 0; w < 4; w++) { int t = ws[w]; ws[w] = s; s += t; }
    total[bkt] = s;
  }
  __syncthreads();
  cnt[bkt * NBH + tid] = ws[wv] + incl - v;
}

// pass 2: scatter into bucket-contiguous staging (per-(block,bucket) runs).
// Bucket bases recomputed in LDS from btotal.
__global__ __launch_bounds__(256) void scatter_coarse(const uint32* __restrict__ epack,
                                                      const int* __restrict__ cnt,
                                                      const int* __restrict__ btotal,
                                                      uint32* __restrict__ staging) {
  __shared__ int shA[256];   // bbase scan -> lcur
  __shared__ int shW[4];
  const int tid = threadIdx.x, lane = tid & 63, wv = tid >> 6;
  // inline exclusive scan of btotal[0..NB_BKT) -> shA
  {
    int v = (tid < NB_BKT) ? btotal[tid] : 0;
    int incl = v;
#pragma unroll
    for (int off = 1; off < 64; off <<= 1) {
      int t = __shfl_up(incl, off, 64);
      if (lane >= off) incl += t;
    }
    if (lane == 63) shW[wv] = incl;
    __syncthreads();
    if (tid == 0) {
      int s = 0;
#pragma unroll
      for (int w = 0; w < 4; w++) { int t = shW[w]; shW[w] = s; s += t; }
    }
    __syncthreads();
    shA[tid] = shW[wv] + incl - v;
  }
  __syncthreads();
  for (int t = tid; t < NB_BKT; t += 256) shA[t] += cnt[t * NBH + blockIdx.x];
  __syncthreads();
  const int chunk = (N_EDGES + NBH - 1) / NBH;
  const int lo = blockIdx.x * chunk;
  const int hi = min(lo + chunk, N_EDGES);
  for (int e = lo + tid; e < hi; e += 256) {
    uint32 pk = epack[e];
    int p = atomicAdd(&shA[pk >> 24], 1);  // bkt = d>>8 = pk>>24
    staging[p] = pk;
  }
}

// pass 3 (fused): per-bucket degree hist + scan + row_start + self-loop slot +
// csr_dst runs + edge placement. One block per bucket; bbase recomputed in LDS.
__global__ __launch_bounds__(256) void build_csr(const uint32* __restrict__ staging,
                                                 const int* __restrict__ btotal,
                                                 int* __restrict__ row_start,
                                                 u16* __restrict__ csr_dst,
                                                 int* __restrict__ csr_src32) {
  __shared__ int shA[256];   // bbase scan, then hist
  __shared__ int shB[256];   // placement cursors
  __shared__ int shW[4];
  const int b = blockIdx.x;
  const int tid = threadIdx.x;
  const int lane = tid & 63, wv = tid >> 6;
  // inline exclusive scan of btotal -> shA
  {
    int v = (tid < NB_BKT) ? btotal[tid] : 0;
    int incl = v;
#pragma unroll
    for (int off = 1; off < 64; off <<= 1) {
      int t = __shfl_up(incl, off, 64);
      if (lane >= off) incl += t;
    }
    if (lane == 63) shW[wv] = incl;
    __syncthreads();
    if (tid == 0) {
      int s = 0;
#pragma unroll
      for (int w = 0; w < 4; w++) { int t = shW[w]; shW[w] = s; s += t; }
    }
    __syncthreads();
    shA[tid] = shW[wv] + incl - v;
  }
  __syncthreads();
  const int lo = shA[b];
  const int hi = lo + btotal[b];
  __syncthreads();
  // degree histogram for this bucket
  shA[tid] = 0;
  __syncthreads();
  for (int i = lo + tid; i < hi; i += 256)
    atomicAdd(&shA[(staging[i] >> 16) & 255], 1);
  __syncthreads();
  int v = shA[tid];
  int incl = v;
#pragma unroll
  for (int off = 1; off < 64; off <<= 1) {
    int t = __shfl_up(incl, off, 64);
    if (lane >= off) incl += t;
  }
  if (lane == 63) shW[wv] = incl;
  __syncthreads();
  if (tid == 0) {
    int s = 0;
#pragma unroll
    for (int w = 0; w < 4; w++) { int t = shW[w]; shW[w] = s; s += t; }
  }
  __syncthreads();
  int excl = shW[wv] + incl - v;
  const int n = (b << 8) + tid;
  if (n < N_NODES) {
    int rs = lo + (b << 8) + excl + tid;  // edges-before + selfloops-before
    row_start[n] = rs;
    csr_src32[rs] = n;  // self-loop at slot rs
    u16 g16 = (u16)n;
    for (int k = 0; k <= v; k++) csr_dst[rs + k] = g16;
    shB[tid] = rs + 1;
  }
  if (b == NB_BKT - 1 && tid == 0) row_start[N_NODES] = N_TOT;
  __syncthreads();
  for (int i = lo + tid; i < hi; i += 256) {
    uint32 pk = staging[i];
    int p = atomicAdd(&shB[(pk >> 16) & 255], 1);
    csr_src32[p] = (int)(pk & 0xffffu);
  }
}

// ---------------- MFMA GEMM: H[M,NCOLS] = X[M,128] @ W[128,NCOLS] ----------------
// One wave per 16-row tile. B from fragment-ordered Wf (L2-resident). No LDS.
// RAWX: A is the raw input x (fp32 or bf16 per flags[0]); conversion fused into
//       the fragment load.
// FUSE_A (layers 1/2): head h owns tiles 2h,2h+1 -> logits in epilogue.
// CMAJOR+FUSE3 (layer 3): class-major store, head-masked logit accumulation,
//       and bf16 1.0 written into pad cols 188..191 (the aggregate3 den column).
template <int NT, int NCOLS, int STRIDE, bool FUSE_A, bool CMAJOR, bool FUSE3, bool RAWX>
__global__ __launch_bounds__(256) void gemm_mfma(const void* __restrict__ X,
                                                 const u16* __restrict__ Wf,
                                                 const u16* __restrict__ attS,
                                                 const u16* __restrict__ attD,
                                                 const int* __restrict__ flags,
                                                 u16* __restrict__ H,
                                                 float* __restrict__ a_s,
                                                 float* __restrict__ a_d, int M) {
  // readfirstlane: prove wave-uniformity of the wave id to the compiler (SGPR loops/addrs)
  const int wid = __builtin_amdgcn_readfirstlane(threadIdx.x >> 6);
  const int lane = threadIdx.x & 63;
  const int row0 = (blockIdx.x * 4 + wid) * 16;
  if (row0 >= M) return;
  const int qr = lane >> 4;   // quad: k-subchunk for A/B, row group for C/D
  const int ln = lane & 15;   // A row within tile / C col within tile

  float4v acc[NT];
#pragma unroll
  for (int t = 0; t < NT; t++) acc[t] = (float4v){0.f, 0.f, 0.f, 0.f};

  const short8* Wf8 = (const short8*)Wf;  // [(t*4 + c)*64 + lane]
  const size_t aoff = (size_t)(row0 + ln) * 128 + qr * 8;
  int f32m = 0;
  if constexpr (RAWX) f32m = flags[0];

#pragma unroll
  for (int c = 0; c < 4; c++) {
    short8 afrag;
    if constexpr (RAWX) {
      if (f32m) {
        const float* ap = (const float*)X + aoff + c * 32;
        float4 lo = ((const float4*)ap)[0];
        float4 hi = ((const float4*)ap)[1];
        afrag[0] = (short)f2b(lo.x); afrag[1] = (short)f2b(lo.y);
        afrag[2] = (short)f2b(lo.z); afrag[3] = (short)f2b(lo.w);
        afrag[4] = (short)f2b(hi.x); afrag[5] = (short)f2b(hi.y);
        afrag[6] = (short)f2b(hi.z); afrag[7] = (short)f2b(hi.w);
      } else {
        afrag = *(const short8*)((const u16*)X + aoff + c * 32);
      }
    } else {
      afrag = *(const short8*)((const u16*)X + aoff + c * 32);
    }
#pragma unroll
    for (int t = 0; t < NT; t++) {
      short8 bfrag = Wf8[(t * 4 + c) * 64 + lane];
      acc[t] = __builtin_amdgcn_mfma_f32_16x16x32_bf16(afrag, bfrag, acc[t], 0, 0, 0);
    }
  }

  // store H (D layout: row = qr*4 + i, col = t*16 + ln)
#pragma unroll
  for (int t = 0; t < NT; t++) {
    int col = t * 16 + ln;
    if (col < NCOLS) {
      int off;
      if constexpr (CMAJOR) {
        int h = (col >= 141) ? 3 : (col >= 94) ? 2 : (col >= 47) ? 1 : 0;
        int c = col - h * 47;
        off = c * 4 + h;
      } else {
        off = col;
      }
#pragma unroll
      for (int i = 0; i < 4; i++) {
        H[(size_t)(row0 + qr * 4 + i) * STRIDE + off] = f2b(acc[t][i]);
      }
    } else {
      if constexpr (CMAJOR) {
        // pad cols 188..191: bf16 1.0 -> aggregate3's den pseudo-class (uint2 col 47)
#pragma unroll
        for (int i = 0; i < 4; i++) {
          H[(size_t)(row0 + qr * 4 + i) * STRIDE + col] = (u16)0x3F80;
        }
      }
    }
  }

  if constexpr (FUSE_A) {
    float aSf[NT], aDf[NT];
#pragma unroll
    for (int t = 0; t < NT; t++) {
      aSf[t] = b2f(attS[t * 16 + ln]);
      aDf[t] = b2f(attD[t * 16 + ln]);
    }
#pragma unroll
    for (int h = 0; h < 4; h++) {
#pragma unroll
      for (int i = 0; i < 4; i++) {
        float s = acc[2 * h][i] * aSf[2 * h] + acc[2 * h + 1][i] * aSf[2 * h + 1];
        float d = acc[2 * h][i] * aDf[2 * h] + acc[2 * h + 1][i] * aDf[2 * h + 1];
#pragma unroll
        for (int m = 1; m < 16; m <<= 1) {
          s += __shfl_xor(s, m, 64);
          d += __shfl_xor(d, m, 64);
        }
        if (ln == 0) {
          int r = row0 + qr * 4 + i;
          a_s[r * 4 + h] = s;
          a_d[r * 4 + h] = d;
        }
      }
    }
  }

  if constexpr (FUSE3) {
    // a_s[n][h] = sum_c H[n][h*47+c] * attS[h*47+c]; col = h*47+c indexes attS directly.
    float sh[4][4], dh[4][4];  // [head][i]
#pragma unroll
    for (int h = 0; h < 4; h++)
#pragma unroll
      for (int i = 0; i < 4; i++) { sh[h][i] = 0.f; dh[h][i] = 0.f; }
#pragma unroll
    for (int t = 0; t < NT; t++) {
      int col = t * 16 + ln;
      bool v = (col < NCOLS);
      float aS = v ? b2f(attS[col]) : 0.f;
      float aD = v ? b2f(attD[col]) : 0.f;
      int hh = (col >= 141) ? 3 : (col >= 94) ? 2 : (col >= 47) ? 1 : 0;
      float aS0 = (hh == 0) ? aS : 0.f, aS1 = (hh == 1) ? aS : 0.f;
      float aS2 = (hh == 2) ? aS : 0.f, aS3 = (hh == 3) ? aS : 0.f;
      float aD0 = (hh == 0) ? aD : 0.f, aD1 = (hh == 1) ? aD : 0.f;
      float aD2 = (hh == 2) ? aD : 0.f, aD3 = (hh == 3) ? aD : 0.f;
#pragma unroll
      for (int i = 0; i < 4; i++) {
        float a = acc[t][i];
        sh[0][i] += a * aS0; sh[1][i] += a * aS1;
        sh[2][i] += a * aS2; sh[3][i] += a * aS3;
        dh[0][i] += a * aD0; dh[1][i] += a * aD1;
        dh[2][i] += a * aD2; dh[3][i] += a * aD3;
      }
    }
#pragma unroll
    for (int h = 0; h < 4; h++) {
#pragma unroll
      for (int i = 0; i < 4; i++) {
        float s = sh[h][i], d = dh[h][i];
#pragma unroll
        for (int m = 1; m < 16; m <<= 1) {
          s += __shfl_xor(s, m, 64);
          d += __shfl_xor(d, m, 64);
        }
        if (ln == 0) {
          int r = row0 + qr * 4 + i;
          a_s[r * 4 + h] = s;
          a_d[r * 4 + h] = d;
        }
      }
    }
  }
}

// ---------------- per-edge softmax weights for layer 3 (unnormalized, packed bf16x4) ----
// w[e][h] = exp(leaky(a_s[src][h] + a_d[dst][h])) as bf16. Self-normalizing: den sums
// the same bf16 values (via the ones pseudo-class), so ratios carry ~2^-9 rel error.
__global__ __launch_bounds__(256) void edge_weights(const int* __restrict__ csr_src,
                                                    const u16* __restrict__ csr_dst,
                                                    const float* __restrict__ a_s,
                                                    const float* __restrict__ a_d,
                                                    uint2* __restrict__ w, int nE) {
  int e = blockIdx.x * blockDim.x + threadIdx.x;
  if (e >= nE) return;
  int s = csr_src[e], d = csr_dst[e];
  float4 as = ((const float4*)a_s)[s];
  float4 ad = ((const float4*)a_d)[d];
  float w0 = __expf(lrelu(as.x + ad.x));
  float w1 = __expf(lrelu(as.y + ad.y));
  float w2 = __expf(lrelu(as.z + ad.z));
  float w3 = __expf(lrelu(as.w + ad.w));
  uint2 o;
  o.x = ((uint32)f2b(w1) << 16) | (uint32)f2b(w0);
  o.y = ((uint32)f2b(w3) << 16) | (uint32)f2b(w2);
  w[e] = o;
}

// ---------------- aggregation (one node per wave; wave-uniform scalar metadata) ----------

// layers 1/2: lane L owns cols 2L,2L+1 (head L>>4). One uint gather/edge/lane.
// Edge weights computed INLINE (fp32, per-lane independent -> no shuffles).
// 8-deep unroll: more outstanding gathers per wave.
__global__ __launch_bounds__(256) void aggregate12(const u16* __restrict__ h,
                                                   const float* __restrict__ a_s,
                                                   const float* __restrict__ a_d,
                                                   const int* __restrict__ row_start,
                                                   const int* __restrict__ csr_src,
                                                   const u16* __restrict__ bias,
                                                   u16* __restrict__ out, int nN) {
  const int lane = threadIdx.x & 63;
  const int wid = __builtin_amdgcn_readfirstlane(threadIdx.x >> 6);  // SGPR wave id
  const int n = blockIdx.x * 4 + wid;
  if (n >= nN) return;
  const int hL = lane >> 4;  // head of cols 2L, 2L+1
  const uint32* h32 = (const uint32*)h;
  const float bias0 = b2f(bias[2 * lane]);
  const float bias1 = b2f(bias[2 * lane + 1]);
  const float adv = a_d[n * 4 + hL];  // wave-row uniform, per head group
  int beg = row_start[n], end = row_start[n + 1];

  float acc0 = 0.f, acc1 = 0.f, den = 0.f;
  int e = beg;
  for (; e + 7 < end; e += 8) {
    int s[8];
    float av[8];
    uint32 g[8];
#pragma unroll
    for (int j = 0; j < 8; j++) s[j] = csr_src[e + j];
#pragma unroll
    for (int j = 0; j < 8; j++) av[j] = a_s[s[j] * 4 + hL];
#pragma unroll
    for (int j = 0; j < 8; j++) g[j] = h32[s[j] * 64 + lane];
#pragma unroll
    for (int j = 0; j < 8; j++) {
      float w = __expf(lrelu(av[j] + adv));
      den += w;
      acc0 += w * lo_bf(g[j]);
      acc1 += w * hi_bf(g[j]);
    }
  }
  for (; e + 3 < end; e += 4) {
    int s[4];
    float av[4];
    uint32 g[4];
#pragma unroll
    for (int j = 0; j < 4; j++) s[j] = csr_src[e + j];
#pragma unroll
    for (int j = 0; j < 4; j++) av[j] = a_s[s[j] * 4 + hL];
#pragma unroll
    for (int j = 0; j < 4; j++) g[j] = h32[s[j] * 64 + lane];
#pragma unroll
    for (int j = 0; j < 4; j++) {
      float w = __expf(lrelu(av[j] + adv));
      den += w;
      acc0 += w * lo_bf(g[j]);
      acc1 += w * hi_bf(g[j]);
    }
  }
  for (; e < end; ++e) {
    int s = csr_src[e];
    float w = __expf(lrelu(a_s[s * 4 + hL] + adv));
    uint32 g = h32[s * 64 + lane];
    den += w;
    acc0 += w * lo_bf(g);
    acc1 += w * hi_bf(g);
  }
  float inv = 1.0f / den;
  float o0 = fmaxf(acc0 * inv + bias0, 0.f);  // relu between layers
  float o1 = fmaxf(acc1 * inv + bias1, 0.f);
  uint32 packed = ((uint32)f2b(o1) << 16) | (uint32)f2b(o0);
  ((uint32*)out)[n * 64 + lane] = packed;
}

// layer 3: class-major h3 (uint2 gather = 4 head vals for class `lane`).
// Weights from the precomputed wbuf (wave-uniform broadcast load, no shuffles
// in the loop); den comes free from the ones pseudo-class accumulated in
// lane 47. mean over heads + bias + log_softmax.
__global__ __launch_bounds__(256) void aggregate3(const u16* __restrict__ h3,
                                                  const uint2* __restrict__ wbuf,
                                                  const int* __restrict__ row_start,
                                                  const int* __restrict__ csr_src,
                                                  const u16* __restrict__ b3,
                                                  const int* __restrict__ flags,
                                                  void* __restrict__ out, int nN) {
  const int lane = threadIdx.x & 63;
  const int wid = __builtin_amdgcn_readfirstlane(threadIdx.x >> 6);  // SGPR wave id
  const int n = blockIdx.x * 4 + wid;
  if (n >= nN) return;
  const bool act = lane < 47;
  const int lidx = (lane <= 47) ? lane : 0;  // lane 47 reads the ones-column -> den
  const float b3v = act ? b2f(b3[lane]) : 0.f;
  const int isf32 = flags[0];
  const uint2* h3v = (const uint2*)h3;  // row = 48 uint2
  int beg = row_start[n], end = row_start[n + 1];

  float acc0 = 0.f, acc1 = 0.f, acc2 = 0.f, acc3 = 0.f;
  int e = beg;
  for (; e + 7 < end; e += 8) {
    int s[8];
    uint2 wp[8];
    uint2 g[8];
#pragma unroll
    for (int j = 0; j < 8; j++) s[j] = csr_src[e + j];
#pragma unroll
    for (int j = 0; j < 8; j++) wp[j] = wbuf[e + j];
#pragma unroll
    for (int j = 0; j < 8; j++) g[j] = h3v[(size_t)s[j] * 48 + lidx];
#pragma unroll
    for (int j = 0; j < 8; j++) {
      float w0 = lo_bf(wp[j].x), w1 = hi_bf(wp[j].x);
      float w2 = lo_bf(wp[j].y), w3 = hi_bf(wp[j].y);
      acc0 += w0 * lo_bf(g[j].x);
      acc1 += w1 * hi_bf(g[j].x);
      acc2 += w2 * lo_bf(g[j].y);
      acc3 += w3 * hi_bf(g[j].y);
    }
  }
  for (; e + 3 < end; e += 4) {
    int s[4];
    uint2 wp[4];
    uint2 g[4];
#pragma unroll
    for (int j = 0; j < 4; j++) s[j] = csr_src[e + j];
#pragma unroll
    for (int j = 0; j < 4; j++) wp[j] = wbuf[e + j];
#pragma unroll
    for (int j = 0; j < 4; j++) g[j] = h3v[(size_t)s[j] * 48 + lidx];
#pragma unroll
    for (int j = 0; j < 4; j++) {
      float w0 = lo_bf(wp[j].x), w1 = hi_bf(wp[j].x);
      float w2 = lo_bf(wp[j].y), w3 = hi_bf(wp[j].y);
      acc0 += w0 * lo_bf(g[j].x);
      acc1 += w1 * hi_bf(g[j].x);
      acc2 += w2 * lo_bf(g[j].y);
      acc3 += w3 * hi_bf(g[j].y);
    }
  }
  for (; e < end; ++e) {
    int s = csr_src[e];
    uint2 wp = wbuf[e];
    uint2 g = h3v[(size_t)s * 48 + lidx];
    float w0 = lo_bf(wp.x), w1 = hi_bf(wp.x);
    float w2 = lo_bf(wp.y), w3 = hi_bf(wp.y);
    acc0 += w0 * lo_bf(g.x);
    acc1 += w1 * hi_bf(g.x);
    acc2 += w2 * lo_bf(g.y);
    acc3 += w3 * hi_bf(g.y);
  }
  // dens live in lane 47's accumulators (w * 1.0 sums, same add order as explicit den)
  float den0 = __shfl(acc0, 47, 64);
  float den1 = __shfl(acc1, 47, 64);
  float den2 = __shfl(acc2, 47, 64);
  float den3 = __shfl(acc3, 47, 64);
  float val = act ? 0.25f * (acc0 / den0 + acc1 / den1 + acc2 / den2 + acc3 / den3) + b3v
                  : -1e30f;
  float mx = val;
#pragma unroll
  for (int m = 1; m < 64; m <<= 1) mx = fmaxf(mx, __shfl_xor(mx, m, 64));
  float ex = act ? __expf(val - mx) : 0.f;
  float sm = ex;
#pragma unroll
  for (int m = 1; m < 64; m <<= 1) sm += __shfl_xor(sm, m, 64);
  float lse = mx + __logf(sm);
  if (act) {
    float r = val - lse;
    if (isf32) ((float*)out)[n * 47 + lane] = r;
    else       ((u16*)out)[n * 47 + lane] = f2b(r);
  }
}

// ---------------- launch ----------------

extern "C" void kernel_launch(void* const* d_in, const int* in_sizes, int n_in,
                              void* d_out, int out_size, void* d_ws, size_t ws_size,
                              hipStream_t stream) {
  const void* x   = d_in[0];
  const void* ei  = d_in[1];
  const void* W1  = d_in[2];
  const void* a1s = d_in[3];
  const void* a1d = d_in[4];
  const void* b1  = d_in[5];
  const void* W2  = d_in[6];
  const void* a2s = d_in[7];
  const void* a2d = d_in[8];
  const void* b2  = d_in[9];
  const void* W3  = d_in[10];
  const void* a3s = d_in[11];
  const void* a3d = d_in[12];
  const void* b3  = d_in[13];
  const int* ei32 = (const int*)ei;

  auto au = [](size_t v) { return (v + 255) & ~(size_t)255; };
  char* p = (char*)d_ws;
  int* flags     = (int*)p; p += 256;
  u16* wt        = (u16*)p; p += au((size_t)58023 * 2);
  u16* Wf1       = (u16*)p; p += au((size_t)16384 * 2);
  u16* Wf2       = (u16*)p; p += au((size_t)16384 * 2);
  u16* Wf3       = (u16*)p; p += au((size_t)24576 * 2);
  int* row_start = (int*)p; p += au((size_t)(N_NODES + 1) * 4);
  int* cnt       = (int*)p; p += au((size_t)NB_BKT * NBH * 4);
  int* btotal    = (int*)p; p += au((size_t)NB_BKT * 4);
  int* csr_src32 = (int*)p; p += au((size_t)N_TOT * 4);
  u16* csr_dst   = (u16*)p; p += au((size_t)N_TOT * 2);
  uint2* wbuf    = (uint2*)p; p += au((size_t)N_TOT * 8);
  float* a_s     = (float*)p; p += au((size_t)N_NODES * 4 * 4);
  float* a_d     = (float*)p; p += au((size_t)N_NODES * 4 * 4);
  u16* hB        = (u16*)p; p += au((size_t)N_NODES * 128 * 2);
  u16* hA        = (u16*)p; p += au((size_t)N_NODES * 128 * 2);
  u16* h3        = (u16*)p; p += au((size_t)N_NODES * 192 * 2);
  // epack/staging alias h3: both consumed before layer 3 writes h3.
  uint32* epack   = (uint32*)h3;               // 3.2 MB
  uint32* staging = (uint32*)(h3 + 1600000);   // next 3.2 MB

  const u16* a1sc = wt + 16384;
  const u16* a1dc = wt + 16512;
  const u16* b1c  = wt + 16640;
  const u16* a2sc = wt + 33152;
  const u16* a2dc = wt + 33280;
  const u16* b2c  = wt + 33408;
  const u16* a3sc = wt + 57600;
  const u16* a3dc = wt + 57788;
  const u16* b3c  = wt + 57976;

  const int gemmBlocks = (N_NODES / 16 + 3) / 4;   // wave per 16-row tile: 782
  const int edgeBlocks = (N_TOT + 255) / 256;

  // CSR build (i64 detect inline) + W reorder (f32 detect inline, publishes flags[0])
  pack_hist<<<NBH, 256, 0, stream>>>(ei32, epack, cnt);
  reorder_all<<<229, 256, 0, stream>>>((const u16*)x, W1, W2, W3, a1s, a1d, b1,
                                       a2s, a2d, b2, a3s, a3d, b3, flags,
                                       Wf1, Wf2, Wf3, wt);
  scan_cols<<<NB_BKT, 256, 0, stream>>>(cnt, btotal);
  scatter_coarse<<<NBH, 256, 0, stream>>>(epack, cnt, btotal, staging);
  build_csr<<<NB_BKT, 256, 0, stream>>>(staging, btotal, row_start, csr_dst, csr_src32);

  // layer 1 (x conversion fused into A-load; logits fused into GEMM epilogue;
  //          weights fused into aggregate)
  gemm_mfma<8, 128, 128, true, false, false, true><<<gemmBlocks, 256, 0, stream>>>(
      x, Wf1, a1sc, a1dc, flags, hA, a_s, a_d, N_NODES);
  aggregate12<<<NODE_BLOCKS, 256, 0, stream>>>(hA, a_s, a_d, row_start, csr_src32,
                                               b1c, hB, N_NODES);

  // layer 2
  gemm_mfma<8, 128, 128, true, false, false, false><<<gemmBlocks, 256, 0, stream>>>(
      hB, Wf2, a2sc, a2dc, flags, hA, a_s, a_d, N_NODES);
  aggregate12<<<NODE_BLOCKS, 256, 0, stream>>>(hA, a_s, a_d, row_start, csr_src32,
                                               b2c, hB, N_NODES);

  // layer 3 (h3 class-major + ones pad col; logits fused via head-masked reduce;
  //          weights precomputed per edge; den from the ones pseudo-class)
  gemm_mfma<12, 188, 192, false, true, true, false><<<gemmBlocks, 256, 0, stream>>>(
      hB, Wf3, a3sc, a3dc, flags, h3, a_s, a_d, N_NODES);
  edge_weights<<<edgeBlocks, 256, 0, stream>>>(csr_src32, csr_dst, a_s, a_d, wbuf, N_TOT);
  aggregate3<<<NODE_BLOCKS, 256, 0, stream>>>(h3, wbuf, row_start, csr_src32,
                                              b3c, flags, d_out, N_NODES);
}